// Round 13
// baseline (185.979 us; speedup 1.0000x reference)
//
#include <hip/hip_runtime.h>
#include <math.h>

#define BDIM 4
#define CDIM 64
#define HDIM 128
#define WDIM 128
#define PLANE (HDIM*WDIM)   // 16384
#define CHW (CDIM*PLANE)    // 1048576

typedef unsigned short ushort_t;
typedef short short8 __attribute__((ext_vector_type(8)));
typedef float floatx4 __attribute__((ext_vector_type(4)));

__device__ inline unsigned int pack_bf16(float lo, float hi) {
  unsigned int ul = __float_as_uint(lo);
  unsigned int uh = __float_as_uint(hi);
  unsigned int rl = (ul + 0x7FFFu + ((ul >> 16) & 1u)) >> 16;   // RNE
  unsigned int rh = (uh + 0x7FFFu + ((uh >> 16) & 1u)) >> 16;
  return (rh << 16) | (rl & 0xFFFFu);
}

// K1: per (b,h): channel-residue sums T[b][h][w][4] and row means xmw[b][c][h].
__global__ __launch_bounds__(256) void k1_T_rowmean(const float* __restrict__ x,
                                                    float* __restrict__ T,
                                                    float* __restrict__ xmw) {
  int bid = blockIdx.x;            // b*128 + h
  int b = bid >> 7, h = bid & 127;
  int t = threadIdx.x;
  int wid = t >> 6, lane = t & 63;
  const float* xp = x + (size_t)b * CHW + h * WDIM;
  float tr[4] = {0,0,0,0}, ur[4] = {0,0,0,0};
#pragma unroll
  for (int cc = 0; cc < 16; cc++) {
    int c = wid * 16 + cc;
    int k = cc & 3;
    float v0 = xp[c * PLANE + lane];
    float v1 = xp[c * PLANE + lane + 64];
    tr[k] += v0; ur[k] += v1;
    float s = v0 + v1;
#pragma unroll
    for (int off = 32; off; off >>= 1) s += __shfl_xor(s, off);
    if (lane == 0) xmw[(b * CDIM + c) * HDIM + h] = s * (1.f / WDIM);
  }
  __shared__ float4 pt[4][128];
  pt[wid][lane]      = make_float4(tr[0], tr[1], tr[2], tr[3]);
  pt[wid][lane + 64] = make_float4(ur[0], ur[1], ur[2], ur[3]);
  __syncthreads();
  if (t < 128) {
    float4 a = pt[0][t], bb = pt[1][t], cvec = pt[2][t], d = pt[3][t];
    float4 s = make_float4(a.x + bb.x + cvec.x + d.x, a.y + bb.y + cvec.y + d.y,
                           a.z + bb.z + cvec.z + d.z, a.w + bb.w + cvec.w + d.w);
    ((float4*)T)[(b * HDIM + h) * WDIM + t] = s;
  }
}

// K2: column means xmh[b][c][w]
__global__ void k2_colmean(const float* __restrict__ x, float* __restrict__ xmh) {
  int bid = blockIdx.x;
  int b = bid >> 6, c = bid & 63;
  int t = threadIdx.x;
  int tw = t & 127, th2 = t >> 7;
  const float* xp = x + (size_t)(b * CDIM + c) * PLANE;
  float s = 0.f;
  for (int h = th2 * 64; h < th2 * 64 + 64; h++) s += xp[h * WDIM + tw];
  __shared__ float sh[256];
  sh[t] = s;
  __syncthreads();
  if (t < 128) xmh[(b * CDIM + c) * WDIM + t] = (sh[t] + sh[t + 128]) * (1.f / HDIM);
}

// K3: enc (bid<256) + group sums Gh/Gw from T (bid>=256)
__global__ void k3_enc_groups(const float* __restrict__ W1, const float* __restrict__ bias1,
                              const float* __restrict__ W2, const float* __restrict__ bias2,
                              const float* __restrict__ xmw, const float* __restrict__ xmh,
                              const float* __restrict__ T,
                              float* __restrict__ ench, float* __restrict__ encw,
                              float* __restrict__ Gh, float* __restrict__ Gw) {
  int bid = blockIdx.x;
  int t = threadIdx.x;
  if (bid < 256) {
    int o = t >> 2, bb = t & 3;
    if (bid < HDIM) {
      int h = bid;
      float s = bias1[o];
      for (int i = 0; i < CDIM; i++) s += W1[o * CDIM + i] * xmw[(bb * CDIM + i) * HDIM + h];
      ench[(o * HDIM + h) * 4 + bb] = s;
    } else {
      int w = bid - HDIM;
      float s = bias2[o];
      for (int i = 0; i < CDIM; i++) s += W2[o * CDIM + i] * xmh[(bb * CDIM + i) * WDIM + w];
      encw[(o * WDIM + w) * 4 + bb] = s;
    }
  } else if (t < 128) {
    int c2 = bid - 256;              // 0..63
    int b = c2 >> 4;
    int w0 = (c2 & 15) * 8;
    const float4* T4 = (const float4*)T;
    float4 s = make_float4(0, 0, 0, 0);
#pragma unroll
    for (int dw = 0; dw < 8; dw++) {
      float4 v = T4[(b * HDIM + t) * WDIM + w0 + dw];
      s.x += v.x; s.y += v.y; s.z += v.z; s.w += v.w;
    }
    ((float4*)Gh)[c2 * HDIM + t] = s;
    float4 s2 = make_float4(0, 0, 0, 0);
#pragma unroll
    for (int dh = 0; dh < 8; dh++) {
      float4 v = T4[(b * HDIM + w0 + dh) * WDIM + t];
      s2.x += v.x; s2.y += v.y; s2.z += v.z; s2.w += v.w;
    }
    ((float4*)Gw)[c2 * WDIM + t] = s2;
  }
}

// K4: per (b,c) plane: 4-way softmax probs. 512 thr: quarter q = branch*2+seg;
// each (branch,p) pair splits the 128-deep dot in half, combined via LDS.
__global__ __launch_bounds__(512) void k4_probs(const float* __restrict__ x,
                                                const float* __restrict__ ench,
                                                const float* __restrict__ encw,
                                                float* __restrict__ Ph,
                                                float* __restrict__ Pw) {
  __shared__ float plane[HDIM * WDIM];
  __shared__ float4 esh[512];
  int bid = blockIdx.x;
  int b = bid >> 6, c = bid & 63;
  int t = threadIdx.x;             // 512
  const float* xp = x + (size_t)(b * CDIM + c) * PLANE;
#pragma unroll 4
  for (int j = 0; j < 32; j++) {
    int idx = j * 512 + t;
    int row = idx >> 7, col = idx & 127;
    plane[row * WDIM + (col ^ (row & 31))] = xp[idx];
  }
  __syncthreads();
  int q = t >> 7, p = t & 127;
  int branch = q >> 1, seg = q & 1;
  int c2 = (b * HDIM + p) >> 3;
  float e0 = 0, e1 = 0, e2 = 0, e3 = 0;
  if (branch == 0) {               // h-branch: p = w
    const float4* E = (const float4*)ench + c2 * HDIM;
    for (int h = seg * 64; h < seg * 64 + 64; h++) {
      float v = plane[h * WDIM + (p ^ (h & 31))];
      float4 e = E[h];
      e0 += v * e.x; e1 += v * e.y; e2 += v * e.z; e3 += v * e.w;
    }
  } else {                         // w-branch: p = h
    const float4* E = (const float4*)encw + c2 * WDIM;
    for (int w = seg * 64; w < seg * 64 + 64; w++) {
      float v = plane[p * WDIM + (w ^ (p & 31))];
      float4 e = E[w];
      e0 += v * e.x; e1 += v * e.y; e2 += v * e.z; e3 += v * e.w;
    }
  }
  esh[t] = make_float4(e0, e1, e2, e3);
  __syncthreads();
  if (seg == 0) {
    float4 o = esh[t + 128];
    e0 += o.x; e1 += o.y; e2 += o.z; e3 += o.w;
    float m = fmaxf(fmaxf(e0, e1), fmaxf(e2, e3));
    float p0 = __expf(e0 - m), p1 = __expf(e1 - m), p2 = __expf(e2 - m), p3 = __expf(e3 - m);
    float sc = 1.f / ((p0 + p1 + p2 + p3) * 128.f);
    float4* dst = (branch == 0) ? (float4*)Ph : (float4*)Pw;
    dst[c2 * 512 + (p & 7) * 64 + c] = make_float4(p0 * sc, p1 * sc, p2 * sc, p3 * sc);
  }
}

// K6prep: bake conv weights into MFMA A-fragment lane order (bf16) + zero part.
__global__ void k6_prep(const float* __restrict__ Wc, ushort_t* __restrict__ afrag,
                        float* __restrict__ part) {
  int idx = blockIdx.x * 256 + threadIdx.x;   // 0..4607
  if (idx < 128) part[idx] = 0.f;
  if (idx >= 4608) return;
  int lane = idx & 63;
  int m = (idx >> 6) & 3;
  int chunk = (idx >> 8) & 1;
  int tap = idx >> 9;
  int dh = tap / 3, dw = tap % 3;
  int o = m * 16 + (lane & 15);
  int ib = chunk * 32 + (lane >> 4) * 8;
  unsigned int d[4];
#pragma unroll
  for (int j = 0; j < 4; j++) {
    float lo = Wc[((size_t)(o * CDIM + ib + 2 * j) * 3 + dh) * 3 + dw];
    float hi = Wc[((size_t)(o * CDIM + ib + 2 * j + 1) * 3 + dh) * 3 + dw];
    d[j] = pack_bf16(lo, hi);
  }
  uint4* dst = (uint4*)afrag + idx;
  *dst = make_uint4(d[0], d[1], d[2], d[3]);
}

// K6: fused attention-output + 3x3 conv (bf16 MFMA implicit GEMM) + BN partials.
// Staging computes out = gamma*(aug_h+aug_w)+x on the fly (k5 inlined; outb deleted).
__global__ __launch_bounds__(512) void k6_conv(const float* __restrict__ x,
                                               const float* __restrict__ Ph,
                                               const float* __restrict__ Pw,
                                               const float* __restrict__ Gh,
                                               const float* __restrict__ Gw,
                                               const float* __restrict__ gamma,
                                               const ushort_t* __restrict__ afrag,
                                               float* __restrict__ yb,
                                               float* __restrict__ part) {
  __shared__ uint4 lds_in[3 * 130 * 4];   // 24960 B
  __shared__ float sh_s[64], sh_ss[64];
  int bid = blockIdx.x;
  int b = bid >> 7, h0 = bid & 127;
  int t = threadIdx.x;
  int lane = t & 63, wv = t >> 6;
  int w0 = wv * 16;
  const float* xb = x + (size_t)b * CHW;
  const float4* Ph4 = (const float4*)Ph;
  const float4* Pw4 = (const float4*)Pw;
  const float4* Gh4 = (const float4*)Gh;
  const float4* Gw4 = (const float4*)Gw;
  float gm = gamma[0];

  if (t < 64) { sh_s[t] = 0.f; sh_ss[t] = 0.f; }

  floatx4 acc[4];
#pragma unroll
  for (int m = 0; m < 4; m++) acc[m] = (floatx4){0.f, 0.f, 0.f, 0.f};

  for (int chunk = 0; chunk < 2; chunk++) {
    int i0 = chunk * 32;
    __syncthreads();
    // ---- stage: fused k5 compute -> bf16 LDS (swizzled ds_write_b128) ----
#pragma unroll
    for (int k = 0; k < 4; k++) {
      int gid = k * 512 + t;
      if (gid < 1560) {
        int wlp = gid % 130;
        int rest = gid / 130;
        int g = rest & 3, lr = rest >> 2;
        int h = h0 - 1 + lr, wl = wlp - 1;
        unsigned int d0 = 0, d1 = 0, d2 = 0, d3 = 0;
        if (h >= 0 && h < HDIM && wl >= 0 && wl < WDIM) {
          int c0 = i0 + g * 8;
          int c2h = (b * HDIM + wl) >> 3;          // k5's decode, tw -> wl
          int c2w = (b * HDIM + h) >> 3;
          float4 gh4 = Gh4[c2h * HDIM + h];
          float4 gw4 = Gw4[c2w * WDIM + wl];
          const float4* php = Ph4 + c2h * 512 + (wl & 7) * 64 + c0;
          const float4* pwp = Pw4 + c2w * 512 + (h & 7) * 64 + c0;
          const float* xpp = xb + (size_t)c0 * PLANE + h * WDIM + wl;
          float v[8];
#pragma unroll
          for (int j = 0; j < 8; j++) {
            float4 ph = php[j], pw = pwp[j];
            float val = ph.x * gh4.x + ph.y * gh4.y + ph.z * gh4.z + ph.w * gh4.w
                      + pw.x * gw4.x + pw.y * gw4.y + pw.z * gw4.z + pw.w * gw4.w;
            v[j] = fmaf(gm, val, xpp[j * PLANE]);
          }
          d0 = pack_bf16(v[0], v[1]); d1 = pack_bf16(v[2], v[3]);
          d2 = pack_bf16(v[4], v[5]); d3 = pack_bf16(v[6], v[7]);
        }
        int pg = g ^ ((wlp >> 1) & 3);
        lds_in[(lr * 130 + wlp) * 4 + pg] = make_uint4(d0, d1, d2, d3);
      }
    }
    __syncthreads();
    // ---- compute: 9 taps x (1 ds_read_b128 + 4 A-loads + 4 MFMA) ----
#pragma unroll
    for (int tap = 0; tap < 9; tap++) {
      int lr = tap / 3, dw = tap % 3;
      int wlp = w0 + (lane & 15) + dw;
      int pg = (lane >> 4) ^ ((wlp >> 1) & 3);
      short8 bf = *(const short8*)&lds_in[(lr * 130 + wlp) * 4 + pg];
      const short8* ap = (const short8*)afrag + (size_t)((tap * 2 + chunk) * 4) * 64 + lane;
#pragma unroll
      for (int m = 0; m < 4; m++) {
        short8 a = ap[m * 64];
        acc[m] = __builtin_amdgcn_mfma_f32_16x16x32_bf16(a, bf, acc[m], 0, 0, 0);
      }
    }
  }
  // ---- epilogue: write C (col=lane&15, row=(lane>>4)*4+j) + BN partials ----
  int col = lane & 15, rg = lane >> 4;
#pragma unroll
  for (int m = 0; m < 4; m++) {
#pragma unroll
    for (int j = 0; j < 4; j++) {
      int o = m * 16 + rg * 4 + j;
      float v = acc[m][j];
      yb[((size_t)(b * CDIM + o) * HDIM + h0) * WDIM + w0 + col] = v;
      float vs = v, vq = v * v;
#pragma unroll
      for (int off = 1; off < 16; off <<= 1) {
        vs += __shfl_xor(vs, off);
        vq += __shfl_xor(vq, off);
      }
      if (col == 0) {
        atomicAdd(&sh_s[o], vs);
        atomicAdd(&sh_ss[o], vq);
      }
    }
  }
  __syncthreads();
  if (t < 64) {
    atomicAdd(&part[t], sh_s[t]);
    atomicAdd(&part[64 + t], sh_ss[t]);
  }
}

// K8: finalize BN stats inline (128 L2-hot floats) + normalize + affine + ReLU
__global__ __launch_bounds__(256) void k8_norm(const float* __restrict__ yb,
                                               const float* __restrict__ part,
                                               const float* __restrict__ bnw,
                                               const float* __restrict__ bnb,
                                               float* __restrict__ out) {
  __shared__ float sa[64], sb2[64];
  int t = threadIdx.x;
  if (t < 64) {
    float s = part[t], ss = part[64 + t];
    float m = s * (1.f / 65536.f);            // B*H*W per channel
    float var = ss * (1.f / 65536.f) - m * m;
    float a = rsqrtf(var + 1e-5f) * bnw[t];
    sa[t] = a;
    sb2[t] = bnb[t] - m * a;
  }
  __syncthreads();
  int idx = blockIdx.x * 256 + t;
  int c = (idx >> 12) & 63;
  float4 v = ((const float4*)yb)[idx];
  float a = sa[c], bb = sb2[c];
  v.x = fmaxf(0.f, v.x * a + bb);
  v.y = fmaxf(0.f, v.y * a + bb);
  v.z = fmaxf(0.f, v.z * a + bb);
  v.w = fmaxf(0.f, v.w * a + bb);
  ((float4*)out)[idx] = v;
}

extern "C" void kernel_launch(void* const* d_in, const int* in_sizes, int n_in,
                              void* d_out, int out_size, void* d_ws, size_t ws_size,
                              hipStream_t stream) {
  const float* x     = (const float*)d_in[0];
  const float* W1    = (const float*)d_in[1];
  const float* b1    = (const float*)d_in[2];
  const float* W2    = (const float*)d_in[3];
  const float* b2    = (const float*)d_in[4];
  const float* Wc    = (const float*)d_in[5];
  const float* bnw   = (const float*)d_in[6];
  const float* bnb   = (const float*)d_in[7];
  const float* gamma = (const float*)d_in[8];
  float* out = (float*)d_out;

  float* ws   = (float*)d_ws;
  float* T    = ws;                 // 262144
  float* xmw  = T    + 262144;      // 32768
  float* xmh  = xmw  + 32768;       // 32768
  float* ench = xmh  + 32768;       // 32768
  float* encw = ench + 32768;       // 32768
  float* Ph   = encw + 32768;       // 131072
  float* Pw   = Ph   + 131072;      // 131072
  float* Gh   = Pw   + 131072;      // 32768
  float* Gw   = Gh   + 32768;       // 32768
  float* yb   = Gw   + 32768;       // 4194304
  float* part = yb   + 4194304;     // 128
  ushort_t* afrag = (ushort_t*)(part + 128);   // 36864 ushorts

  k6_prep       <<<18, 256, 0, stream>>>(Wc, afrag, part);
  k1_T_rowmean  <<<512, 256, 0, stream>>>(x, T, xmw);
  k2_colmean    <<<256, 256, 0, stream>>>(x, xmh);
  k3_enc_groups <<<320, 256, 0, stream>>>(W1, b1, W2, b2, xmw, xmh, T, ench, encw, Gh, Gw);
  k4_probs      <<<256, 512, 0, stream>>>(x, ench, encw, Ph, Pw);
  k6_conv       <<<512, 512, 0, stream>>>(x, Ph, Pw, Gh, Gw, gamma, afrag, yb, part);
  k8_norm       <<<4096, 256, 0, stream>>>(yb, part, bnw, bnb, out);
}